// Round 8
// baseline (316.266 us; speedup 1.0000x reference)
//
#include <hip/hip_runtime.h>
#include <hip/hip_bf16.h>

typedef unsigned short u16t;
typedef unsigned int   u32t;
typedef float  f32x4 __attribute__((ext_vector_type(4)));
typedef short  s16x8 __attribute__((ext_vector_type(8)));
typedef unsigned int u32x4 __attribute__((ext_vector_type(4)));
typedef float  f4 __attribute__((ext_vector_type(4)));

#define BB 2
#define TT 2048
#define CC 2048
#define HH 16
#define KVHN 4
#define DD 128
#define EPSV 1.1920929e-07f
#define SCALE 0.08838834764831845f
#define MFIX 12.0f   // fixed softmax max: |q.k|*SCALE <= sqrt(128)*(1+bf16 err) < 11.5

__device__ __forceinline__ float b2f(u16t u){ union{u32t i; float f;} x; x.i=((u32t)u)<<16; return x.f; }
__device__ __forceinline__ u16t f2b(float f){ union{float f; u32t i;} x; x.f=f; u32t r = x.i + 0x7fffu + ((x.i>>16)&1u); return (u16t)(r>>16); }
__device__ __forceinline__ u32t pk2(float a, float b){
    __hip_bfloat162 h = __float22bfloat162_rn(make_float2(a,b));
    u32t r; __builtin_memcpy(&r,&h,4); return r;
}
__device__ __forceinline__ s16x8 ldf(const u16t* p){ s16x8 r; __builtin_memcpy(&r,p,16); return r; }
__device__ __forceinline__ void st16(u16t* p, u32x4 v){ __builtin_memcpy(p,&v,16); }
__device__ __forceinline__ u32x4 ldg16(const u16t* p){ u32x4 r; __builtin_memcpy(&r,p,16); return r; }

// async global->LDS, 16B per lane; LDS dest = wave-uniform base + lane*16
typedef const __attribute__((address_space(1))) unsigned int ga_u32;
typedef __attribute__((address_space(3))) unsigned int ls_u32;
__device__ __forceinline__ void gl16(const u16t* g, u16t* l) {
    __builtin_amdgcn_global_load_lds((ga_u32*)(unsigned long long)(g),
                                     (ls_u32*)(unsigned int)(unsigned long long)(l),
                                     16, 0, 0);
}

#define BARRIER() __builtin_amdgcn_s_barrier()
#define SCHEDB()  __builtin_amdgcn_sched_barrier(0)
#define WAITLG0() asm volatile("s_waitcnt lgkmcnt(0)" ::: "memory")
#define WAITLG4() asm volatile("s_waitcnt lgkmcnt(4)" ::: "memory")
#define WAITVM6() asm volatile("s_waitcnt vmcnt(6)" ::: "memory")
#define WAITVM5() asm volatile("s_waitcnt vmcnt(5)" ::: "memory")
#define WAITVM4() asm volatile("s_waitcnt vmcnt(4)" ::: "memory")
#define WAITVM0() asm volatile("s_waitcnt vmcnt(0)" ::: "memory")

// ---------------- Kernel 0: fp32 -> bf16 conversion ----------------
__global__ __launch_bounds__(256) void cvt_kernel(
    const float* __restrict__ x,  const float* __restrict__ wq,
    const float* __restrict__ wk, const float* __restrict__ wv,
    const float* __restrict__ wo,
    u16t* __restrict__ xb, u16t* __restrict__ wqb, u16t* __restrict__ wkb,
    u16t* __restrict__ wvb, u16t* __restrict__ wob)
{
    size_t g = (size_t)blockIdx.x * 256 + threadIdx.x;
    const float* src; u16t* dst; size_t off;
    if      (g < 1048576) { src = x;  dst = xb;  off = g; }
    else if (g < 1572864) { src = wq; dst = wqb; off = g - 1048576; }
    else if (g < 1703936) { src = wk; dst = wkb; off = g - 1572864; }
    else if (g < 1835008) { src = wv; dst = wvb; off = g - 1703936; }
    else                  { src = wo; dst = wob; off = g - 1835008; }
    f4 a = *(const f4*)(src + off*8);
    f4 b = *(const f4*)(src + off*8 + 4);
    u32x4 o = { pk2(a[0],a[1]), pk2(a[2],a[3]), pk2(b[0],b[1]), pk2(b[2],b[3]) };
    st16(dst + off*8, o);
}

// ---------------- Shared 256xBN fine-interleaved GEMM core (unchanged r6) ----------------
template<int NF, bool BSW>
__device__ __forceinline__ void gemm256(
    const u16t* __restrict__ aPanel, const u16t* __restrict__ bPanel,
    u16t* lds, f32x4 (&acc)[4][NF], const int tid)
{
    constexpr int BQ = NF/2;            // bf frags per phase per wave
    constexpr int BS = NF/4;            // gl16 groups per B nh-slab (2 or 1)
    u16t* Abuf[2] = { lds,         lds + 16384 };
    u16t* Bbuf[2] = { lds + 32768, lds + 32768 + NF*2048 };
    const int w = tid>>6, quad = (tid>>4)&3, l15 = tid&15;
    const int wr = (w>>1)*64, wc = (w&1)*(BQ*16);
    const int gcol = (((tid&7) ^ ((tid>>3)&7)) << 3);
    const u16t* aB  = aPanel + (size_t)(tid>>3)*CC + gcol;
    const u16t* bBr = bPanel + (size_t)(tid>>3)*CC + gcol;

    #pragma unroll
    for (int i=0;i<4;++i)
        #pragma unroll
        for (int j=0;j<NF;++j)
            #pragma unroll
            for (int r=0;r<4;++r) acc[i][j][r] = 0.f;

    // prologue: tile0 complete, then tile1's A + B-lo (B-hi(1) comes at kt0 ph1)
    #pragma unroll
    for (int i=0;i<4;++i) gl16(aB + (size_t)(i*64)*CC, Abuf[0] + (i*512+tid)*8);
    #pragma unroll
    for (int s=0;s<2*BS;++s){
        const int ss = BSW ? ((s==1)?2:((s==2)?1:s)) : s;
        gl16(bBr + (size_t)(ss*64)*CC, Bbuf[0] + (s*512+tid)*8);
    }
    SCHEDB();
    #pragma unroll
    for (int i=0;i<4;++i) gl16(aB + (size_t)(i*64)*CC + 64, Abuf[1] + (i*512+tid)*8);
    #pragma unroll
    for (int s=0;s<BS;++s){
        const int ss = BSW ? ((s==1)?2:s) : s;
        gl16(bBr + (size_t)(ss*64)*CC + 64, Bbuf[1] + (s*512+tid)*8);
    }

    s16x8 af0[4], af1[4], bf[BQ];

    #pragma unroll 2
    for (int kt=0; kt<32; ++kt){
        const u16t* Ac = Abuf[kt&1];
        const u16t* Bc = Bbuf[kt&1];
        u16t* An = Abuf[kt&1];
        u16t* Bn = Bbuf[kt&1];
        u16t* Bo = Bbuf[(kt+1)&1];
        if (kt == 31) { WAITVM0(); }
        else { if constexpr (NF==8) { WAITVM6(); } else { WAITVM5(); } }
        SCHEDB();
        BARRIER();                      // tile kt fully resident for all waves

        // ---- ph0 (nh0,kh0): all A reads + bf; lgkm(4) leaves af1 in flight
        #pragma unroll
        for (int mi=0;mi<4;++mi){
            const int row = wr + mi*16 + l15;
            af0[mi] = ldf(Ac + row*64 + ((quad ^ (row&7))<<3));
        }
        #pragma unroll
        for (int ni=0;ni<BQ;++ni){
            const int row = wc + ni*16 + l15;
            bf[ni] = ldf(Bc + row*64 + ((quad ^ (row&7))<<3));
        }
        #pragma unroll
        for (int mi=0;mi<4;++mi){
            const int row = wr + mi*16 + l15;
            af1[mi] = ldf(Ac + row*64 + (((4|quad) ^ (row&7))<<3));
        }
        SCHEDB();
        BARRIER();
        WAITLG4();
        SCHEDB();
        __builtin_amdgcn_s_setprio(1);
        #pragma unroll
        for (int mi=0;mi<4;++mi)
            #pragma unroll
            for (int ni=0;ni<BQ;++ni)
                acc[mi][ni] = __builtin_amdgcn_mfma_f32_16x16x32_bf16(
                    af0[mi], bf[ni], acc[mi][ni], 0,0,0);
        __builtin_amdgcn_s_setprio(0);

        // ---- ph1 (nh0,kh1); stage B-hi(kt+1) into the other buffer
        #pragma unroll
        for (int ni=0;ni<BQ;++ni){
            const int row = wc + ni*16 + l15;
            bf[ni] = ldf(Bc + row*64 + (((4|quad) ^ (row&7))<<3));
        }
        if (kt < 31){
            #pragma unroll
            for (int s=0;s<BS;++s){
                const int sl = BS + s;
                const int ss = BSW ? ((sl==2)?1:sl) : sl;
                gl16(bBr + (size_t)(ss*64)*CC + (kt+1)*64, Bo + (sl*512+tid)*8);
            }
        }
        SCHEDB();
        BARRIER();
        WAITLG0();
        SCHEDB();
        __builtin_amdgcn_s_setprio(1);
        #pragma unroll
        for (int mi=0;mi<4;++mi)
            #pragma unroll
            for (int ni=0;ni<BQ;++ni)
                acc[mi][ni] = __builtin_amdgcn_mfma_f32_16x16x32_bf16(
                    af1[mi], bf[ni], acc[mi][ni], 0,0,0);
        __builtin_amdgcn_s_setprio(0);

        // ---- ph2 (nh1,kh0); stage A(kt+2) into this buffer (A freed after ph0/ph1)
        #pragma unroll
        for (int ni=0;ni<BQ;++ni){
            const int row = NF*16 + wc + ni*16 + l15;
            bf[ni] = ldf(Bc + row*64 + ((quad ^ (row&7))<<3));
        }
        if (kt < 30){
            #pragma unroll
            for (int i=0;i<4;++i)
                gl16(aB + (size_t)(i*64)*CC + (kt+2)*64, An + (i*512+tid)*8);
        }
        SCHEDB();
        BARRIER();
        WAITLG0();
        SCHEDB();
        __builtin_amdgcn_s_setprio(1);
        #pragma unroll
        for (int mi=0;mi<4;++mi)
            #pragma unroll
            for (int ni=0;ni<BQ;++ni)
                acc[mi][BQ+ni] = __builtin_amdgcn_mfma_f32_16x16x32_bf16(
                    af0[mi], bf[ni], acc[mi][BQ+ni], 0,0,0);
        __builtin_amdgcn_s_setprio(0);

        // ---- ph3 (nh1,kh1); stage B-lo(kt+2) into this buffer (freed after ph1)
        #pragma unroll
        for (int ni=0;ni<BQ;++ni){
            const int row = NF*16 + wc + ni*16 + l15;
            bf[ni] = ldf(Bc + row*64 + (((4|quad) ^ (row&7))<<3));
        }
        if (kt < 30){
            #pragma unroll
            for (int s=0;s<BS;++s){
                const int ss = BSW ? ((s==1)?2:s) : s;
                gl16(bBr + (size_t)(ss*64)*CC + (kt+2)*64, Bn + (s*512+tid)*8);
            }
        }
        SCHEDB();
        BARRIER();
        WAITLG0();
        SCHEDB();
        __builtin_amdgcn_s_setprio(1);
        #pragma unroll
        for (int mi=0;mi<4;++mi)
            #pragma unroll
            for (int ni=0;ni<BQ;++ni)
                acc[mi][BQ+ni] = __builtin_amdgcn_mfma_f32_16x16x32_bf16(
                    af1[mi], bf[ni], acc[mi][BQ+ni], 0,0,0);
        __builtin_amdgcn_s_setprio(0);
    }
}

// ---------------- Kernel 1: QKV GEMM + in-register RoPE + RMSNorm (unchanged r6) ----------------
__global__ __launch_bounds__(512,2) void qkv_kernel(
    const u16t* __restrict__ xb, const u16t* __restrict__ wqb,
    const u16t* __restrict__ wkb, const u16t* __restrict__ wvb,
    const float* __restrict__ cosp, const float* __restrict__ sinp,
    u16t* __restrict__ qws, u16t* __restrict__ kws, u16t* __restrict__ vtw)
{
    __shared__ __align__(16) u16t lds[65536];
    const int tid = threadIdx.x;
    const int bx = blockIdx.x, by = blockIdx.y;
    const int m0 = bx*256;

    int type, headbase; const u16t* W;
    if (by < 8)       { type=0; W = wqb + (size_t)by*256*CC;      headbase = by*2; }
    else if (by < 10) { type=1; W = wkb + (size_t)(by-8)*256*CC;  headbase = (by-8)*2; }
    else              { type=2; W = wvb + (size_t)(by-10)*256*CC; headbase = (by-10)*2; }

    f32x4 acc[4][8];
    gemm256<8,true>(xb + (size_t)m0*CC, W, lds, acc, tid);

    const int w = tid>>6, quad = (tid>>4)&3, l15 = tid&15;
    const int wr = (w>>1)*64, wn = w&1;
    const int head = headbase + wn;
    const int bb = bx>>3;
    const int ttb = (m0 + wr) & 2047;

    if (type == 2){
        u16t* vb = vtw + (size_t)(bb*KVHN+head)*DD*TT;
        #pragma unroll
        for (int mi=0;mi<4;++mi){
            const int tt = ttb + mi*16 + quad*4;
            #pragma unroll
            for (int ni=0;ni<8;++ni){
                const int d = ((ni>>2)*64) + ((ni&3)*16) + l15;
                u16t o[4];
                #pragma unroll
                for (int r=0;r<4;++r) o[r] = f2b(acc[mi][ni][r]);
                __builtin_memcpy(vb + (size_t)d*TT + tt, o, 8);
            }
        }
    } else {
        u16t* dst = (type==0) ? (qws + (size_t)(bb*HH+head)*TT*DD)
                              : (kws + (size_t)(bb*KVHN+head)*TT*DD);
        #pragma unroll
        for (int mi=0;mi<4;++mi){
            const int tt0 = ttb + mi*16 + quad*4;
            float ss[4] = {0.f,0.f,0.f,0.f};
            #pragma unroll
            for (int ni=0;ni<8;++ni)
                #pragma unroll
                for (int r=0;r<4;++r) ss[r] += acc[mi][ni][r]*acc[mi][ni][r];
            float rms[4];
            #pragma unroll
            for (int r=0;r<4;++r){
                float s = ss[r];
                s += __shfl_xor(s, 1, 16);
                s += __shfl_xor(s, 2, 16);
                s += __shfl_xor(s, 4, 16);
                s += __shfl_xor(s, 8, 16);
                rms[r] = rsqrtf(s*(1.f/128.f) + EPSV);
            }
            #pragma unroll
            for (int ni=0;ni<4;++ni){
                const int j = ni*16 + l15;
                #pragma unroll
                for (int r=0;r<4;++r){
                    const int tt = tt0 + r;
                    const float c = cosp[tt*64 + j];
                    const float s = sinp[tt*64 + j];
                    const float z1 = acc[mi][ni][r], z2 = acc[mi][ni+4][r];
                    dst[(size_t)tt*DD + j]      = f2b((z1*c + z2*s)*rms[r]);
                    dst[(size_t)tt*DD + j + 64] = f2b((z2*c - z1*s)*rms[r]);
                }
            }
        }
    }
}

// ---------------- Kernel 2: causal flash attention ----------------
// r6 structure VERBATIM (s[2][4], mi loops, pf[2], single uniform guard) with
// only the bases substituted: mi=0 = 16 rows of the LONG tile (qb0), mi=1 =
// 16 rows of the SHORT tile (qb1). All 8 waves compute-active on every k-tile
// -> 2 active waves/SIMD. Short-tile far iterations are zeroed EXACTLY by the
// causal mask (nm true, all kcol>qrow+r -> p=0) — no new control flow vs r6.
__global__ __launch_bounds__(512,2) void attn_kernel(
    const u16t* __restrict__ qws, const u16t* __restrict__ kws,
    const u16t* __restrict__ vtw, u16t* __restrict__ yws)
{
    __shared__ __align__(16) u16t lds[49152];   // 96 KiB
    u16t* Ps = lds + 32768;

    const int tid = threadIdx.x;
    const int w = tid>>6, lane = tid&63, quad = lane>>4, l15 = lane&15;
    const int bx = blockIdx.x, h = blockIdx.y, b = blockIdx.z, kvh = h>>2;

    const int qb0 = (15-bx)*128 + w*16;   // long tile rows (mi=0)
    const int qb1 = bx*128 + w*16;        // short tile rows (mi=1)
    const int nkt = (16 - bx)*2;

    const u16t* kb = kws + (size_t)(b*KVHN+kvh)*TT*DD;
    const u16t* vb = vtw + (size_t)(b*KVHN+kvh)*DD*TT;

    const int krow = tid>>4;
    const int kcg  = (tid&15) ^ ((tid>>4)&7);
    const int vrow = tid>>3;
    const int vcg  = (tid&7)  ^ ((tid>>3)&7);

    // Q fragments: direct global->reg (8 loads, drained by first vmcnt(4))
    const u16t* qbb = qws + (size_t)(b*HH+h)*TT*DD;
    s16x8 qf[2][4];
    #pragma unroll
    for (int kq=0;kq<4;++kq)
        qf[0][kq] = ldf(qbb + (size_t)(qb0 + l15)*DD + kq*32 + quad*8);
    #pragma unroll
    for (int kq=0;kq<4;++kq)
        qf[1][kq] = ldf(qbb + (size_t)(qb1 + l15)*DD + kq*32 + quad*8);

    {
        u16t* Kd = lds;        u16t* Vd = lds + 16384;
        gl16(kb + (size_t)(krow)*DD + kcg*8,        Kd + tid*8);
        gl16(kb + (size_t)(krow+32)*DD + kcg*8,     Kd + (512+tid)*8);
        gl16(vb + (size_t)(vrow)*TT + vcg*8,        Vd + tid*8);
        gl16(vb + (size_t)(vrow+64)*TT + vcg*8,     Vd + (512+tid)*8);
        SCHEDB();   // keep tile-0 staging strictly before tile-1 (vmcnt ledger)
        Kd = lds + 8192;       Vd = lds + 24576;
        gl16(kb + (size_t)(krow+64)*DD + kcg*8,      Kd + tid*8);
        gl16(kb + (size_t)(krow+96)*DD + kcg*8,      Kd + (512+tid)*8);
        gl16(vb + (size_t)(vrow)*TT + 64 + vcg*8,    Vd + tid*8);
        gl16(vb + (size_t)(vrow+64)*TT + 64 + vcg*8, Vd + (512+tid)*8);
    }

    f32x4 o_[2][8];
    float l_[2][4];
    #pragma unroll
    for (int mi=0;mi<2;++mi){
        #pragma unroll
        for (int r=0;r<4;++r) l_[mi][r] = 0.f;
        #pragma unroll
        for (int n8=0;n8<8;++n8)
            #pragma unroll
            for (int r=0;r<4;++r) o_[mi][n8][r] = 0.f;
    }

    const int swz = (l15&7)<<3;

    for (int kt=0; kt<nkt; ++kt){
        const int k0 = kt*64;
        if (kt+1 == nkt) { WAITVM0(); } else { WAITVM4(); }
        SCHEDB();
        BARRIER();
        if (k0 <= qb0 + 15) {           // long group active (superset of short)
            const u16t* Ks = (kt&1) ? (lds + 8192)  : lds;
            const u16t* Vt = (kt&1) ? (lds + 24576) : (lds + 16384);

            // S = Q K^T
            f32x4 s[2][4];
            #pragma unroll
            for (int mi=0;mi<2;++mi)
                #pragma unroll
                for (int ni=0;ni<4;++ni)
                    #pragma unroll
                    for (int r=0;r<4;++r) s[mi][ni][r] = 0.f;
            #pragma unroll
            for (int kq=0;kq<4;++kq){
                s16x8 kf[4];
                #pragma unroll
                for (int ni=0;ni<4;++ni)
                    kf[ni] = ldf(Ks + (ni*16+l15)*128 + (((kq*4+quad)<<3) ^ swz));
                __builtin_amdgcn_s_setprio(1);
                #pragma unroll
                for (int mi=0;mi<2;++mi)
                    #pragma unroll
                    for (int ni=0;ni<4;++ni)
                        s[mi][ni] = __builtin_amdgcn_mfma_f32_16x16x32_bf16(qf[mi][kq], kf[ni], s[mi][ni], 0,0,0);
                __builtin_amdgcn_s_setprio(0);
            }

            // fixed-max softmax: p = exp(s*SCALE - 12); exact per-mi mask
            #pragma unroll
            for (int mi=0;mi<2;++mi){
                const int qb = mi ? qb1 : qb0;
                const bool nm = (k0 + 63) > qb;
                const int qrow = qb + quad*4;
                #pragma unroll
                for (int ni=0;ni<4;++ni){
                    const int kcol = k0 + ni*16 + l15;
                    #pragma unroll
                    for (int r=0;r<4;++r){
                        float p = __expf(__builtin_fmaf(s[mi][ni][r], SCALE, -MFIX));
                        if (nm && kcol > qrow + r) p = 0.f;
                        l_[mi][r] += p;
                        const int rw = w*32 + mi*16 + quad*4 + r;
                        Ps[rw*64 + ((ni*16+l15) ^ (((quad*4+r)&7)<<3))] = f2b(p);
                    }
                }
            }

            // O += P V  (same-wave LDS round-trip; DS ops in-order, no barrier)
            #pragma unroll
            for (int ks=0;ks<2;++ks){
                s16x8 pf[2];
                #pragma unroll
                for (int mi=0;mi<2;++mi)
                    pf[mi] = ldf(Ps + (w*32+mi*16+l15)*64 + (((ks*4+quad)<<3) ^ swz));
                __builtin_amdgcn_s_setprio(1);
                #pragma unroll
                for (int n8=0;n8<8;++n8){
                    s16x8 vf = ldf(Vt + (n8*16+l15)*64 + (((ks*4+quad)<<3) ^ swz));
                    #pragma unroll
                    for (int mi=0;mi<2;++mi)
                        o_[mi][n8] = __builtin_amdgcn_mfma_f32_16x16x32_bf16(pf[mi], vf, o_[mi][n8], 0,0,0);
                }
                __builtin_amdgcn_s_setprio(0);
            }
        }
        BARRIER();
        if (kt+2 < nkt){
            const int kn = (kt+2)*64;
            u16t* Kd = (kt&1) ? (lds + 8192)  : lds;
            u16t* Vd = (kt&1) ? (lds + 24576) : (lds + 16384);
            gl16(kb + (size_t)(kn+krow)*DD + kcg*8,      Kd + tid*8);
            gl16(kb + (size_t)(kn+krow+32)*DD + kcg*8,   Kd + (512+tid)*8);
            gl16(vb + (size_t)(vrow)*TT + kn + vcg*8,    Vd + tid*8);
            gl16(vb + (size_t)(vrow+64)*TT + kn + vcg*8, Vd + (512+tid)*8);
        }
    }

    // epilogue: reduce l across the 16 col-lanes, normalize, store y[b][t][h*128+d]
    #pragma unroll
    for (int mi=0;mi<2;++mi){
        const int qrow = (mi ? qb1 : qb0) + quad*4;
        float inv[4];
        #pragma unroll
        for (int r=0;r<4;++r){
            float lt = l_[mi][r];
            lt += __shfl_xor(lt,1,16);
            lt += __shfl_xor(lt,2,16);
            lt += __shfl_xor(lt,4,16);
            lt += __shfl_xor(lt,8,16);
            inv[r] = 1.f/lt;
        }
        #pragma unroll
        for (int n8=0;n8<8;++n8)
            #pragma unroll
            for (int r=0;r<4;++r)
                yws[((size_t)(b*TT + qrow + r))*2048 + h*DD + n8*16 + l15] = f2b(o_[mi][n8][r]*inv[r]);
    }
}

// ---------------- Kernel 3: output projection (256x128 tiles, 256 blocks) ----------------
__global__ __launch_bounds__(512,2) void oproj_kernel(
    const u16t* __restrict__ y, const u16t* __restrict__ wob, float* __restrict__ out)
{
    __shared__ __align__(16) u16t lds[49152];   // 96 KiB (NF=4)
    const int tid = threadIdx.x;
    const int m0 = blockIdx.x*256, n0 = blockIdx.y*128;

    f32x4 acc[4][4];
    gemm256<4,false>(y + (size_t)m0*CC, wob + (size_t)n0*CC, lds, acc, tid);

    const int w = tid>>6, quad = (tid>>4)&3, l15 = tid&15;
    const int wr = (w>>1)*64, wcq = (w&1)*32;
    #pragma unroll
    for (int mi=0;mi<4;++mi){
        const int m = m0 + wr + mi*16 + quad*4;
        #pragma unroll
        for (int ni=0;ni<4;++ni){
            const int n = n0 + ((ni>>1)*64) + wcq + ((ni&1)*16) + l15;
            #pragma unroll
            for (int r=0;r<4;++r)
                out[(size_t)(m+r)*CC + n] = acc[mi][ni][r];
        }
    }
}

extern "C" void kernel_launch(void* const* d_in, const int* in_sizes, int n_in,
                              void* d_out, int out_size, void* d_ws, size_t ws_size,
                              hipStream_t stream) {
    const float* x    = (const float*)d_in[0];
    const float* cosp = (const float*)d_in[1];
    const float* sinp = (const float*)d_in[2];
    const float* Wq   = (const float*)d_in[3];
    const float* Wk   = (const float*)d_in[4];
    const float* Wv   = (const float*)d_in[5];
    const float* Wo   = (const float*)d_in[6];

    u16t* ws  = (u16t*)d_ws;
    u16t* xb  = ws;                          // 8388608 elems (aliased by yws after qkv)
    u16t* wqb = xb  + 8388608;               // 4194304
    u16t* wkb = wqb + 4194304;               // 1048576
    u16t* wvb = wkb + 1048576;               // 1048576
    u16t* wob = wvb + 1048576;               // 4194304
    u16t* qws = wob + 4194304;               // 8388608
    u16t* kws = qws + 8388608;               // 2097152
    u16t* vtw = kws + 2097152;               // 2097152
    u16t* yws = xb;                          // alias: xb dead after qkv_kernel
    float* out = (float*)d_out;

    cvt_kernel<<<dim3(9216), 256, 0, stream>>>(x, Wq, Wk, Wv, Wo, xb, wqb, wkb, wvb, wob);
    qkv_kernel<<<dim3(16, 12), 512, 0, stream>>>(xb, wqb, wkb, wvb, cosp, sinp, qws, kws, vtw);
    attn_kernel<<<dim3(8, 16, 2), 512, 0, stream>>>(qws, kws, vtw, yws);
    oproj_kernel<<<dim3(16, 16), 512, 0, stream>>>(yws, wob, out);
}

// Round 9
// 300.602 us; speedup vs baseline: 1.0521x; 1.0521x over previous
//
#include <hip/hip_runtime.h>
#include <hip/hip_bf16.h>

typedef unsigned short u16t;
typedef unsigned int   u32t;
typedef float  f32x4 __attribute__((ext_vector_type(4)));
typedef short  s16x8 __attribute__((ext_vector_type(8)));
typedef unsigned int u32x4 __attribute__((ext_vector_type(4)));
typedef float  f4 __attribute__((ext_vector_type(4)));

#define BB 2
#define TT 2048
#define CC 2048
#define HH 16
#define KVHN 4
#define DD 128
#define EPSV 1.1920929e-07f
#define SCALE 0.08838834764831845f
#define MFIX 12.0f   // fixed softmax max: |q.k|*SCALE <= sqrt(128)*(1+bf16 err) < 11.5

__device__ __forceinline__ float b2f(u16t u){ union{u32t i; float f;} x; x.i=((u32t)u)<<16; return x.f; }
__device__ __forceinline__ u16t f2b(float f){ union{float f; u32t i;} x; x.f=f; u32t r = x.i + 0x7fffu + ((x.i>>16)&1u); return (u16t)(r>>16); }
__device__ __forceinline__ u32t pk2(float a, float b){
    __hip_bfloat162 h = __float22bfloat162_rn(make_float2(a,b));
    u32t r; __builtin_memcpy(&r,&h,4); return r;
}
__device__ __forceinline__ s16x8 ldf(const u16t* p){ s16x8 r; __builtin_memcpy(&r,p,16); return r; }
__device__ __forceinline__ void st16(u16t* p, u32x4 v){ __builtin_memcpy(p,&v,16); }
__device__ __forceinline__ u32x4 ldg16(const u16t* p){ u32x4 r; __builtin_memcpy(&r,p,16); return r; }

// async global->LDS, 16B per lane; LDS dest = wave-uniform base + lane*16
typedef const __attribute__((address_space(1))) unsigned int ga_u32;
typedef __attribute__((address_space(3))) unsigned int ls_u32;
__device__ __forceinline__ void gl16(const u16t* g, u16t* l) {
    __builtin_amdgcn_global_load_lds((ga_u32*)(unsigned long long)(g),
                                     (ls_u32*)(unsigned int)(unsigned long long)(l),
                                     16, 0, 0);
}

#define BARRIER() __builtin_amdgcn_s_barrier()
#define SCHEDB()  __builtin_amdgcn_sched_barrier(0)
#define WAITLG0() asm volatile("s_waitcnt lgkmcnt(0)" ::: "memory")
#define WAITLG4() asm volatile("s_waitcnt lgkmcnt(4)" ::: "memory")
#define WAITVM8() asm volatile("s_waitcnt vmcnt(8)" ::: "memory")
#define WAITVM6() asm volatile("s_waitcnt vmcnt(6)" ::: "memory")
#define WAITVM5() asm volatile("s_waitcnt vmcnt(5)" ::: "memory")
#define WAITVM0() asm volatile("s_waitcnt vmcnt(0)" ::: "memory")

// ---------------- Kernel 0: fp32 -> bf16 conversion ----------------
__global__ __launch_bounds__(256) void cvt_kernel(
    const float* __restrict__ x,  const float* __restrict__ wq,
    const float* __restrict__ wk, const float* __restrict__ wv,
    const float* __restrict__ wo,
    u16t* __restrict__ xb, u16t* __restrict__ wqb, u16t* __restrict__ wkb,
    u16t* __restrict__ wvb, u16t* __restrict__ wob)
{
    size_t g = (size_t)blockIdx.x * 256 + threadIdx.x;
    const float* src; u16t* dst; size_t off;
    if      (g < 1048576) { src = x;  dst = xb;  off = g; }
    else if (g < 1572864) { src = wq; dst = wqb; off = g - 1048576; }
    else if (g < 1703936) { src = wk; dst = wkb; off = g - 1572864; }
    else if (g < 1835008) { src = wv; dst = wvb; off = g - 1703936; }
    else                  { src = wo; dst = wob; off = g - 1835008; }
    f4 a = *(const f4*)(src + off*8);
    f4 b = *(const f4*)(src + off*8 + 4);
    u32x4 o = { pk2(a[0],a[1]), pk2(a[2],a[3]), pk2(b[0],b[1]), pk2(b[2],b[3]) };
    st16(dst + off*8, o);
}

// ---------------- Shared 256xBN fine-interleaved GEMM core (unchanged r6) ----------------
template<int NF, bool BSW>
__device__ __forceinline__ void gemm256(
    const u16t* __restrict__ aPanel, const u16t* __restrict__ bPanel,
    u16t* lds, f32x4 (&acc)[4][NF], const int tid)
{
    constexpr int BQ = NF/2;            // bf frags per phase per wave
    constexpr int BS = NF/4;            // gl16 groups per B nh-slab (2 or 1)
    u16t* Abuf[2] = { lds,         lds + 16384 };
    u16t* Bbuf[2] = { lds + 32768, lds + 32768 + NF*2048 };
    const int w = tid>>6, quad = (tid>>4)&3, l15 = tid&15;
    const int wr = (w>>1)*64, wc = (w&1)*(BQ*16);
    const int gcol = (((tid&7) ^ ((tid>>3)&7)) << 3);
    const u16t* aB  = aPanel + (size_t)(tid>>3)*CC + gcol;
    const u16t* bBr = bPanel + (size_t)(tid>>3)*CC + gcol;

    #pragma unroll
    for (int i=0;i<4;++i)
        #pragma unroll
        for (int j=0;j<NF;++j)
            #pragma unroll
            for (int r=0;r<4;++r) acc[i][j][r] = 0.f;

    // prologue: tile0 complete, then tile1's A + B-lo (B-hi(1) comes at kt0 ph1)
    #pragma unroll
    for (int i=0;i<4;++i) gl16(aB + (size_t)(i*64)*CC, Abuf[0] + (i*512+tid)*8);
    #pragma unroll
    for (int s=0;s<2*BS;++s){
        const int ss = BSW ? ((s==1)?2:((s==2)?1:s)) : s;
        gl16(bBr + (size_t)(ss*64)*CC, Bbuf[0] + (s*512+tid)*8);
    }
    SCHEDB();
    #pragma unroll
    for (int i=0;i<4;++i) gl16(aB + (size_t)(i*64)*CC + 64, Abuf[1] + (i*512+tid)*8);
    #pragma unroll
    for (int s=0;s<BS;++s){
        const int ss = BSW ? ((s==1)?2:s) : s;
        gl16(bBr + (size_t)(ss*64)*CC + 64, Bbuf[1] + (s*512+tid)*8);
    }

    s16x8 af0[4], af1[4], bf[BQ];

    #pragma unroll 2
    for (int kt=0; kt<32; ++kt){
        const u16t* Ac = Abuf[kt&1];
        const u16t* Bc = Bbuf[kt&1];
        u16t* An = Abuf[kt&1];
        u16t* Bn = Bbuf[kt&1];
        u16t* Bo = Bbuf[(kt+1)&1];
        if (kt == 31) { WAITVM0(); }
        else { if constexpr (NF==8) { WAITVM6(); } else { WAITVM5(); } }
        SCHEDB();
        BARRIER();                      // tile kt fully resident for all waves

        // ---- ph0 (nh0,kh0): all A reads + bf; lgkm(4) leaves af1 in flight
        #pragma unroll
        for (int mi=0;mi<4;++mi){
            const int row = wr + mi*16 + l15;
            af0[mi] = ldf(Ac + row*64 + ((quad ^ (row&7))<<3));
        }
        #pragma unroll
        for (int ni=0;ni<BQ;++ni){
            const int row = wc + ni*16 + l15;
            bf[ni] = ldf(Bc + row*64 + ((quad ^ (row&7))<<3));
        }
        #pragma unroll
        for (int mi=0;mi<4;++mi){
            const int row = wr + mi*16 + l15;
            af1[mi] = ldf(Ac + row*64 + (((4|quad) ^ (row&7))<<3));
        }
        SCHEDB();
        BARRIER();
        WAITLG4();
        SCHEDB();
        __builtin_amdgcn_s_setprio(1);
        #pragma unroll
        for (int mi=0;mi<4;++mi)
            #pragma unroll
            for (int ni=0;ni<BQ;++ni)
                acc[mi][ni] = __builtin_amdgcn_mfma_f32_16x16x32_bf16(
                    af0[mi], bf[ni], acc[mi][ni], 0,0,0);
        __builtin_amdgcn_s_setprio(0);

        // ---- ph1 (nh0,kh1); stage B-hi(kt+1) into the other buffer
        #pragma unroll
        for (int ni=0;ni<BQ;++ni){
            const int row = wc + ni*16 + l15;
            bf[ni] = ldf(Bc + row*64 + (((4|quad) ^ (row&7))<<3));
        }
        if (kt < 31){
            #pragma unroll
            for (int s=0;s<BS;++s){
                const int sl = BS + s;
                const int ss = BSW ? ((sl==2)?1:sl) : sl;
                gl16(bBr + (size_t)(ss*64)*CC + (kt+1)*64, Bo + (sl*512+tid)*8);
            }
        }
        SCHEDB();
        BARRIER();
        WAITLG0();
        SCHEDB();
        __builtin_amdgcn_s_setprio(1);
        #pragma unroll
        for (int mi=0;mi<4;++mi)
            #pragma unroll
            for (int ni=0;ni<BQ;++ni)
                acc[mi][ni] = __builtin_amdgcn_mfma_f32_16x16x32_bf16(
                    af1[mi], bf[ni], acc[mi][ni], 0,0,0);
        __builtin_amdgcn_s_setprio(0);

        // ---- ph2 (nh1,kh0); stage A(kt+2) into this buffer (A freed after ph0/ph1)
        #pragma unroll
        for (int ni=0;ni<BQ;++ni){
            const int row = NF*16 + wc + ni*16 + l15;
            bf[ni] = ldf(Bc + row*64 + ((quad ^ (row&7))<<3));
        }
        if (kt < 30){
            #pragma unroll
            for (int i=0;i<4;++i)
                gl16(aB + (size_t)(i*64)*CC + (kt+2)*64, An + (i*512+tid)*8);
        }
        SCHEDB();
        BARRIER();
        WAITLG0();
        SCHEDB();
        __builtin_amdgcn_s_setprio(1);
        #pragma unroll
        for (int mi=0;mi<4;++mi)
            #pragma unroll
            for (int ni=0;ni<BQ;++ni)
                acc[mi][BQ+ni] = __builtin_amdgcn_mfma_f32_16x16x32_bf16(
                    af0[mi], bf[ni], acc[mi][BQ+ni], 0,0,0);
        __builtin_amdgcn_s_setprio(0);

        // ---- ph3 (nh1,kh1); stage B-lo(kt+2) into this buffer (freed after ph1)
        #pragma unroll
        for (int ni=0;ni<BQ;++ni){
            const int row = NF*16 + wc + ni*16 + l15;
            bf[ni] = ldf(Bc + row*64 + (((4|quad) ^ (row&7))<<3));
        }
        if (kt < 30){
            #pragma unroll
            for (int s=0;s<BS;++s){
                const int ss = BSW ? ((s==1)?2:s) : s;
                gl16(bBr + (size_t)(ss*64)*CC + (kt+2)*64, Bn + (s*512+tid)*8);
            }
        }
        SCHEDB();
        BARRIER();
        WAITLG0();
        SCHEDB();
        __builtin_amdgcn_s_setprio(1);
        #pragma unroll
        for (int mi=0;mi<4;++mi)
            #pragma unroll
            for (int ni=0;ni<BQ;++ni)
                acc[mi][BQ+ni] = __builtin_amdgcn_mfma_f32_16x16x32_bf16(
                    af1[mi], bf[ni], acc[mi][BQ+ni], 0,0,0);
        __builtin_amdgcn_s_setprio(0);
    }
}

// ---------------- Kernel 1: QKV GEMM + in-register RoPE + RMSNorm (unchanged r6) ----------------
__global__ __launch_bounds__(512,2) void qkv_kernel(
    const u16t* __restrict__ xb, const u16t* __restrict__ wqb,
    const u16t* __restrict__ wkb, const u16t* __restrict__ wvb,
    const float* __restrict__ cosp, const float* __restrict__ sinp,
    u16t* __restrict__ qws, u16t* __restrict__ kws, u16t* __restrict__ vtw)
{
    __shared__ __align__(16) u16t lds[65536];
    const int tid = threadIdx.x;
    const int bx = blockIdx.x, by = blockIdx.y;
    const int m0 = bx*256;

    int type, headbase; const u16t* W;
    if (by < 8)       { type=0; W = wqb + (size_t)by*256*CC;      headbase = by*2; }
    else if (by < 10) { type=1; W = wkb + (size_t)(by-8)*256*CC;  headbase = (by-8)*2; }
    else              { type=2; W = wvb + (size_t)(by-10)*256*CC; headbase = (by-10)*2; }

    f32x4 acc[4][8];
    gemm256<8,true>(xb + (size_t)m0*CC, W, lds, acc, tid);

    const int w = tid>>6, quad = (tid>>4)&3, l15 = tid&15;
    const int wr = (w>>1)*64, wn = w&1;
    const int head = headbase + wn;
    const int bb = bx>>3;
    const int ttb = (m0 + wr) & 2047;

    if (type == 2){
        u16t* vb = vtw + (size_t)(bb*KVHN+head)*DD*TT;
        #pragma unroll
        for (int mi=0;mi<4;++mi){
            const int tt = ttb + mi*16 + quad*4;
            #pragma unroll
            for (int ni=0;ni<8;++ni){
                const int d = ((ni>>2)*64) + ((ni&3)*16) + l15;
                u16t o[4];
                #pragma unroll
                for (int r=0;r<4;++r) o[r] = f2b(acc[mi][ni][r]);
                __builtin_memcpy(vb + (size_t)d*TT + tt, o, 8);
            }
        }
    } else {
        u16t* dst = (type==0) ? (qws + (size_t)(bb*HH+head)*TT*DD)
                              : (kws + (size_t)(bb*KVHN+head)*TT*DD);
        #pragma unroll
        for (int mi=0;mi<4;++mi){
            const int tt0 = ttb + mi*16 + quad*4;
            float ss[4] = {0.f,0.f,0.f,0.f};
            #pragma unroll
            for (int ni=0;ni<8;++ni)
                #pragma unroll
                for (int r=0;r<4;++r) ss[r] += acc[mi][ni][r]*acc[mi][ni][r];
            float rms[4];
            #pragma unroll
            for (int r=0;r<4;++r){
                float s = ss[r];
                s += __shfl_xor(s, 1, 16);
                s += __shfl_xor(s, 2, 16);
                s += __shfl_xor(s, 4, 16);
                s += __shfl_xor(s, 8, 16);
                rms[r] = rsqrtf(s*(1.f/128.f) + EPSV);
            }
            #pragma unroll
            for (int ni=0;ni<4;++ni){
                const int j = ni*16 + l15;
                #pragma unroll
                for (int r=0;r<4;++r){
                    const int tt = tt0 + r;
                    const float c = cosp[tt*64 + j];
                    const float s = sinp[tt*64 + j];
                    const float z1 = acc[mi][ni][r], z2 = acc[mi][ni+4][r];
                    dst[(size_t)tt*DD + j]      = f2b((z1*c + z2*s)*rms[r]);
                    dst[(size_t)tt*DD + j + 64] = f2b((z2*c - z1*s)*rms[r]);
                }
            }
        }
    }
}

// ---------------- Kernel 2: causal flash attention ----------------
// 256 threads / 4 waves, one 128-row q-tile per block (r5 per-wave structure
// VERBATIM). LDS exactly 80 KiB -> 2 blocks/CU; grid (16,16,2)=512 blocks.
// Complementary dispatch order (qti = b ? bx : 15-bx) makes the two
// co-resident blocks on a CU long+short (17 tiles total) -> balanced, and
// cross-block desync gives MFMA||VALU overlap without masked-zero waste (r8
// lesson). vmcnt ledger: Q(8)+T0(8)+T1(8) outstanding; wait vmcnt(8)/tile.
__global__ __launch_bounds__(256,2) void attn_kernel(
    const u16t* __restrict__ qws, const u16t* __restrict__ kws,
    const u16t* __restrict__ vtw, u16t* __restrict__ yws)
{
    __shared__ __align__(16) u16t lds[40960];   // 80 KiB exactly
    // u16 offsets: K0 0, K1 8192, V0 16384, V1 24576, Ps 32768 ([128][64] swz)
    u16t* Ps = lds + 32768;

    const int tid = threadIdx.x;
    const int w = tid>>6, lane = tid&63, quad = lane>>4, l15 = lane&15;
    const int bx = blockIdx.x, h = blockIdx.y, b = blockIdx.z, kvh = h>>2;

    const int qti    = b ? bx : (15 - bx);   // co-resident pair sums to 17 tiles
    const int qwbase = qti*128 + w*32;       // absolute first q-row of this wave
    const int nkt    = (qti+1)*2;

    const u16t* kb = kws + (size_t)(b*KVHN+kvh)*TT*DD;
    const u16t* vb = vtw + (size_t)(b*KVHN+kvh)*DD*TT;

    // staging constants; rows step by 16/32 (0 mod 8) so the same inverse
    // swizzle column granule applies to all four gl16 of a tile
    const int krow = tid>>4;                     // 0..15
    const int kcg  = (tid&15) ^ ((tid>>4)&7);
    const int vrow = tid>>3;                     // 0..31
    const int vcg  = (tid&7)  ^ ((tid>>3)&7);

    // Q fragments: direct global->reg (8 loads; drained by kt=0's vmcnt(8))
    const u16t* qp = qws + ((size_t)(b*HH+h)*TT + qwbase + l15)*DD + quad*8;
    s16x8 qf[2][4];
    #pragma unroll
    for (int mi=0;mi<2;++mi)
        #pragma unroll
        for (int kq=0;kq<4;++kq)
            qf[mi][kq] = ldf(qp + (size_t)mi*16*DD + kq*32);
    SCHEDB();   // pin Q loads before staging (vmcnt ledger)

    // prologue: stage tiles 0 and 1 (8 gl16/thread each)
    {
        u16t* Kd = lds;        u16t* Vd = lds + 16384;
        #pragma unroll
        for (int j=0;j<4;++j)
            gl16(kb + (size_t)(krow + j*16)*DD + kcg*8,      Kd + (j*256+tid)*8);
        #pragma unroll
        for (int j=0;j<4;++j)
            gl16(vb + (size_t)(vrow + j*32)*TT + vcg*8,      Vd + (j*256+tid)*8);
        SCHEDB();   // tile-0 staging strictly before tile-1
        Kd = lds + 8192;       Vd = lds + 24576;
        #pragma unroll
        for (int j=0;j<4;++j)
            gl16(kb + (size_t)(64 + krow + j*16)*DD + kcg*8, Kd + (j*256+tid)*8);
        #pragma unroll
        for (int j=0;j<4;++j)
            gl16(vb + (size_t)(vrow + j*32)*TT + 64 + vcg*8, Vd + (j*256+tid)*8);
    }

    f32x4 o_[2][8];
    float l_[2][4];
    #pragma unroll
    for (int mi=0;mi<2;++mi){
        #pragma unroll
        for (int r=0;r<4;++r) l_[mi][r] = 0.f;
        #pragma unroll
        for (int n8=0;n8<8;++n8)
            #pragma unroll
            for (int r=0;r<4;++r) o_[mi][n8][r] = 0.f;
    }

    const int swz = (l15&7)<<3;   // read-side XOR (u16 units) for K/V/Ps b128 reads

    for (int kt=0; kt<nkt; ++kt){
        const int k0 = kt*64;
        if (kt+1 == nkt) { WAITVM0(); } else { WAITVM8(); }
        SCHEDB();
        BARRIER();                                   // tile kt visible to all waves
        if (k0 <= qwbase + 31) {
            const u16t* Ks = (kt&1) ? (lds + 8192)  : lds;           // [64][128] swz
            const u16t* Vt = (kt&1) ? (lds + 24576) : (lds + 16384); // [128][64] swz

            // S = Q K^T
            f32x4 s[2][4];
            #pragma unroll
            for (int mi=0;mi<2;++mi)
                #pragma unroll
                for (int ni=0;ni<4;++ni)
                    #pragma unroll
                    for (int r=0;r<4;++r) s[mi][ni][r] = 0.f;
            #pragma unroll
            for (int kq=0;kq<4;++kq){
                s16x8 kf[4];
                #pragma unroll
                for (int ni=0;ni<4;++ni)
                    kf[ni] = ldf(Ks + (ni*16+l15)*128 + (((kq*4+quad)<<3) ^ swz));
                __builtin_amdgcn_s_setprio(1);
                #pragma unroll
                for (int mi=0;mi<2;++mi)
                    #pragma unroll
                    for (int ni=0;ni<4;++ni)
                        s[mi][ni] = __builtin_amdgcn_mfma_f32_16x16x32_bf16(qf[mi][kq], kf[ni], s[mi][ni], 0,0,0);
                __builtin_amdgcn_s_setprio(0);
            }

            // fixed-max softmax: p = exp(s*SCALE - 12)
            const bool need_mask = (k0 + 63) > qwbase;
            #pragma unroll
            for (int mi=0;mi<2;++mi){
                const int qrow = qwbase + mi*16 + quad*4;
                #pragma unroll
                for (int ni=0;ni<4;++ni){
                    const int kcol = k0 + ni*16 + l15;
                    #pragma unroll
                    for (int r=0;r<4;++r){
                        float p = __expf(__builtin_fmaf(s[mi][ni][r], SCALE, -MFIX));
                        if (need_mask && kcol > qrow + r) p = 0.f;
                        l_[mi][r] += p;
                        const int rw = w*32 + mi*16 + quad*4 + r;
                        Ps[rw*64 + ((ni*16+l15) ^ (((quad*4+r)&7)<<3))] = f2b(p);
                    }
                }
            }

            // O += P V  (same-wave LDS round-trip; DS ops in-order, no barrier)
            #pragma unroll
            for (int ks=0;ks<2;++ks){
                s16x8 pf[2];
                #pragma unroll
                for (int mi=0;mi<2;++mi)
                    pf[mi] = ldf(Ps + (w*32+mi*16+l15)*64 + (((ks*4+quad)<<3) ^ swz));
                __builtin_amdgcn_s_setprio(1);
                #pragma unroll
                for (int n8=0;n8<8;++n8){
                    s16x8 vf = ldf(Vt + (n8*16+l15)*64 + (((ks*4+quad)<<3) ^ swz));
                    #pragma unroll
                    for (int mi=0;mi<2;++mi)
                        o_[mi][n8] = __builtin_amdgcn_mfma_f32_16x16x32_bf16(pf[mi], vf, o_[mi][n8], 0,0,0);
                }
                __builtin_amdgcn_s_setprio(0);
            }
        }
        BARRIER();                                   // all reads of buf (kt&1) done
        if (kt+2 < nkt){                             // restage just-freed buffer
            const int kn = (kt+2)*64;
            u16t* Kd = (kt&1) ? (lds + 8192)  : lds;
            u16t* Vd = (kt&1) ? (lds + 24576) : (lds + 16384);
            #pragma unroll
            for (int j=0;j<4;++j)
                gl16(kb + (size_t)(kn + krow + j*16)*DD + kcg*8, Kd + (j*256+tid)*8);
            #pragma unroll
            for (int j=0;j<4;++j)
                gl16(vb + (size_t)(vrow + j*32)*TT + kn + vcg*8, Vd + (j*256+tid)*8);
        }
    }

    // epilogue: reduce l across the 16 col-lanes, normalize, store y[b][t][h*128+d]
    #pragma unroll
    for (int mi=0;mi<2;++mi){
        const int qrow = qwbase + mi*16 + quad*4;
        float inv[4];
        #pragma unroll
        for (int r=0;r<4;++r){
            float lt = l_[mi][r];
            lt += __shfl_xor(lt,1,16);
            lt += __shfl_xor(lt,2,16);
            lt += __shfl_xor(lt,4,16);
            lt += __shfl_xor(lt,8,16);
            inv[r] = 1.f/lt;
        }
        #pragma unroll
        for (int n8=0;n8<8;++n8)
            #pragma unroll
            for (int r=0;r<4;++r)
                yws[((size_t)(b*TT + qrow + r))*2048 + h*DD + n8*16 + l15] = f2b(o_[mi][n8][r]*inv[r]);
    }
}

// ---------------- Kernel 3: output projection (256x128 tiles, 256 blocks) ----------------
__global__ __launch_bounds__(512,2) void oproj_kernel(
    const u16t* __restrict__ y, const u16t* __restrict__ wob, float* __restrict__ out)
{
    __shared__ __align__(16) u16t lds[49152];   // 96 KiB (NF=4)
    const int tid = threadIdx.x;
    const int m0 = blockIdx.x*256, n0 = blockIdx.y*128;

    f32x4 acc[4][4];
    gemm256<4,false>(y + (size_t)m0*CC, wob + (size_t)n0*CC, lds, acc, tid);

    const int w = tid>>6, quad = (tid>>4)&3, l15 = tid&15;
    const int wr = (w>>1)*64, wcq = (w&1)*32;
    #pragma unroll
    for (int mi=0;mi<4;++mi){
        const int m = m0 + wr + mi*16 + quad*4;
        #pragma unroll
        for (int ni=0;ni<4;++ni){
            const int n = n0 + ((ni>>1)*64) + wcq + ((ni&1)*16) + l15;
            #pragma unroll
            for (int r=0;r<4;++r)
                out[(size_t)(m+r)*CC + n] = acc[mi][ni][r];
        }
    }
}

extern "C" void kernel_launch(void* const* d_in, const int* in_sizes, int n_in,
                              void* d_out, int out_size, void* d_ws, size_t ws_size,
                              hipStream_t stream) {
    const float* x    = (const float*)d_in[0];
    const float* cosp = (const float*)d_in[1];
    const float* sinp = (const float*)d_in[2];
    const float* Wq   = (const float*)d_in[3];
    const float* Wk   = (const float*)d_in[4];
    const float* Wv   = (const float*)d_in[5];
    const float* Wo   = (const float*)d_in[6];

    u16t* ws  = (u16t*)d_ws;
    u16t* xb  = ws;                          // 8388608 elems (aliased by yws after qkv)
    u16t* wqb = xb  + 8388608;               // 4194304
    u16t* wkb = wqb + 4194304;               // 1048576
    u16t* wvb = wkb + 1048576;               // 1048576
    u16t* wob = wvb + 1048576;               // 4194304
    u16t* qws = wob + 4194304;               // 8388608
    u16t* kws = qws + 8388608;               // 2097152
    u16t* vtw = kws + 2097152;               // 2097152
    u16t* yws = xb;                          // alias: xb dead after qkv_kernel
    float* out = (float*)d_out;

    cvt_kernel<<<dim3(9216), 256, 0, stream>>>(x, Wq, Wk, Wv, Wo, xb, wqb, wkb, wvb, wob);
    qkv_kernel<<<dim3(16, 12), 512, 0, stream>>>(xb, wqb, wkb, wvb, cosp, sinp, qws, kws, vtw);
    attn_kernel<<<dim3(16, 16, 2), 256, 0, stream>>>(qws, kws, vtw, yws);
    oproj_kernel<<<dim3(16, 16), 512, 0, stream>>>(yws, wob, out);
}